// Round 1
// 74.118 us; speedup vs baseline: 1.0004x; 1.0004x over previous
//
#include <hip/hip_runtime.h>

// HandGNNEncoder: fused GCN(2->64) + relu + GCN(64->128) + mean-pool.
// Exact algebraic rewrite:
//   y = A_norm @ x                                    (sparse, 44 nnz)
//   z = sum_t wpool[t] * relu(y[t,:] @ W1 + b1)       (64-vector / graph)
//   out = z @ W2 + b2                                  (128 / graph)
// This revision (latency/occupancy-focused):
//   * cooperative fully-coalesced x -> LDS staging (no 4x duplicate loads)
//   * y fused into the z-loop (y[21] register array eliminated, -42 VGPR)
//   * single block-wide barrier; zb is wave-local -> s_waitcnt lgkmcnt(0)
//   * b2 folded into MFMA C-init (epilogue = pure stores)
//   * LDS 39.7 KB + __launch_bounds__(256,4) -> 4 blocks/CU target

typedef __attribute__((ext_vector_type(8))) short short8;
typedef __attribute__((ext_vector_type(4))) float float4v;
typedef __attribute__((ext_vector_type(2))) float float2v;

namespace {
constexpr float RS2 = 0.70710678118654752f;
constexpr float RS3 = 0.57735026918962576f;
constexpr float RS6 = 0.40824829046386302f;
constexpr float TH  = 1.0f / 3.0f;
constexpr float HF  = 0.5f;

constexpr int ROW_PTR[22] = {0,1,3,5,7,9,11,13,15,17,20,22,24,26,29,31,33,35,38,40,42,44};
constexpr int COL[44] = {
  0,
  0,1,  1,2,  2,3,  3,4,
  0,5,  5,6,  6,7,  7,8,
  0,5,9,   9,10, 10,11, 11,12,
  0,9,13,  13,14, 14,15, 15,16,
  0,13,17, 17,18, 18,19, 19,20
};
constexpr float AW[44] = {
  1.0f,
  RS2,HF,  HF,HF,  HF,HF,  HF,HF,
  RS2,HF,  HF,HF,  HF,HF,  HF,HF,
  RS3,RS6,TH,  RS6,HF,  HF,HF,  HF,HF,
  RS3,TH,TH,   RS6,HF,  HF,HF,  HF,HF,
  RS3,TH,TH,   RS6,HF,  HF,HF,  HF,HF
};
constexpr float WPOOL[21] = {
  (1.0f + 2.0f*RS2 + 3.0f*RS3)/21.0f,
  1.0f/21.0f, 1.0f/21.0f, 1.0f/21.0f, 0.5f/21.0f,
  (1.0f+RS6)/21.0f,        1.0f/21.0f, 1.0f/21.0f, 0.5f/21.0f,
  (2.0f/3.0f+RS6)/21.0f,   1.0f/21.0f, 1.0f/21.0f, 0.5f/21.0f,
  (2.0f/3.0f+RS6)/21.0f,   1.0f/21.0f, 1.0f/21.0f, 0.5f/21.0f,
  (1.0f/3.0f+RS6)/21.0f,   1.0f/21.0f, 1.0f/21.0f, 0.5f/21.0f
};

// bf16 LDS row stride: 64 + 8 pad = 144 B = 9*16 keeps 16B alignment for
// b128 frag reads and breaks power-of-2 bank strides (8 phases, optimal).
constexpr int ZS = 72;
// xsh stride in float2 units (21 -> 168 B rows; read pattern <=2-way = free).
constexpr int XP = 21;
} // namespace

__device__ __forceinline__ unsigned short f2bf(float v) {
  unsigned u = __float_as_uint(v);
  u += 0x7fffu + ((u >> 16) & 1u);   // round-to-nearest-even
  return (unsigned short)(u >> 16);
}

__global__ __launch_bounds__(256, 4) void gnn_mfma(
    const float* __restrict__ x,   // [G,21,2]
    const float* __restrict__ W1,  // [2,64]
    const float* __restrict__ b1,  // [64]
    const float* __restrict__ W2,  // [64,128]
    const float* __restrict__ b2,  // [128]
    float* __restrict__ out,       // [G,128]
    int G)
{
  __shared__ __align__(16) float sW1[128];
  __shared__ __align__(16) float sb1[64];
  __shared__ __align__(16) float sb2[128];
  __shared__ __align__(16) unsigned short w2t[128 * ZS]; // W2^T bf16: [n=128][k=64+pad]
  __shared__ __align__(16) unsigned short zb[64 * ZS];   // z bf16:    [g=64 ][k=64+pad]
  __shared__ __align__(8)  float2 xsh[64 * XP];          // staged x:  [g=64 ][21]

  const int tid = threadIdx.x;
  const int g0  = blockIdx.x * 64;
  const int gl  = tid >> 2;        // graph within block (0..63)
  const int qd  = tid & 3;         // feature quarter   (0..3)

  // ---- cooperative, fully-coalesced x load, issued FIRST so its HBM
  // latency drains behind the W2 staging below. 64*21 = 1344 float2/block.
  const float2* xb = (const float2*)x + (size_t)g0 * 21;
  const int lim = G * 21 - g0 * 21;    // remaining float2 in x
  float2 xv[6];
  #pragma unroll
  for (int r = 0; r < 6; ++r) {
    const int i = tid + r * 256;
    xv[r] = (i < 1344 && i < lim) ? xb[i] : make_float2(0.f, 0.f);
  }

  // ---- stage small weights.
  if (tid < 128) { sW1[tid] = W1[tid]; sb2[tid] = b2[tid]; }
  if (tid < 64)  { sb1[tid] = b1[tid]; }

  // ---- stage W2 -> bf16 transposed; thread owns (n, k-half):
  // 32 coalesced dword loads, 4 b128 LDS writes.
  {
    const int n  = tid & 127;
    const int k0 = (tid >> 7) * 32;
    unsigned int wp[16];
    #pragma unroll
    for (int r = 0; r < 16; ++r) {
      const float v0 = W2[(k0 + 2 * r) * 128 + n];
      const float v1 = W2[(k0 + 2 * r + 1) * 128 + n];
      wp[r] = (unsigned)f2bf(v0) | (((unsigned)f2bf(v1)) << 16);
    }
    uint4* wd = (uint4*)&w2t[n * ZS + k0];
    wd[0] = make_uint4(wp[0],  wp[1],  wp[2],  wp[3]);
    wd[1] = make_uint4(wp[4],  wp[5],  wp[6],  wp[7]);
    wd[2] = make_uint4(wp[8],  wp[9],  wp[10], wp[11]);
    wd[3] = make_uint4(wp[12], wp[13], wp[14], wp[15]);
  }

  // ---- park x in LDS (writes are contiguous across tids -> conflict-free).
  #pragma unroll
  for (int r = 0; r < 6; ++r) {
    const int i = tid + r * 256;
    if (i < 1344) xsh[i] = xv[r];
  }

  __syncthreads();   // the ONLY block-wide barrier: xsh, sW1/sb1/sb2, w2t ready

  // ---- pull this graph's x back into registers (21 x ds_read_b64,
  // 4-lane broadcast per row, <=2-way bank aliasing = free).
  float2v xs[21];
  #pragma unroll
  for (int t = 0; t < 21; ++t) {
    const float2 v = xsh[gl * XP + t];
    xs[t] = (float2v){v.x, v.y};
  }

  // ---- fused front-end + z: y[t] computed on the fly (no y[21] array),
  // this thread's 16 features (f = qd*16 + 2j, 2j+1), packed f32.
  {
    float2v u0p[8], u1p[8], bvp[8], accp[8];
    #pragma unroll
    for (int j = 0; j < 8; ++j) {
      u0p[j]  = *(const float2v*)&sW1[qd * 16 + 2 * j];
      u1p[j]  = *(const float2v*)&sW1[64 + qd * 16 + 2 * j];
      bvp[j]  = *(const float2v*)&sb1[qd * 16 + 2 * j];
      accp[j] = (float2v){0.f, 0.f};
    }
    #pragma unroll
    for (int t = 0; t < 21; ++t) {
      // y[t] = (A_norm @ x)[t], packed over (x,y) coords.
      float2v a = (float2v){0.f, 0.f};
      #pragma unroll
      for (int e = ROW_PTR[t]; e < ROW_PTR[t + 1]; ++e) {
        const float2v aw = {AW[e], AW[e]};
        a = __builtin_elementwise_fma(aw, xs[COL[e]], a);
      }
      const float2v y0b = {a[0], a[0]};
      const float2v y1b = {a[1], a[1]};
      const float2v wpb = {WPOOL[t], WPOOL[t]};
      #pragma unroll
      for (int j = 0; j < 8; ++j) {
        float2v r = __builtin_elementwise_fma(
            y0b, u0p[j], __builtin_elementwise_fma(y1b, u1p[j], bvp[j]));
        r = __builtin_elementwise_max(r, (float2v){0.f, 0.f});
        accp[j] = __builtin_elementwise_fma(wpb, r, accp[j]);
      }
    }
    unsigned int zp[8];
    #pragma unroll
    for (int j = 0; j < 8; ++j)
      zp[j] = (unsigned)f2bf(accp[j][0]) | (((unsigned)f2bf(accp[j][1])) << 16);
    uint4* zd = (uint4*)&zb[gl * ZS + qd * 16];
    zd[0] = make_uint4(zp[0], zp[1], zp[2], zp[3]);
    zd[1] = make_uint4(zp[4], zp[5], zp[6], zp[7]);
  }

  // Wave w's MFMA B-operand reads exactly zb rows w*16..w*16+15, which were
  // written by wave w's own threads -> no block barrier needed, just drain
  // this wave's LDS writes. ("memory" clobber orders the surrounding ds ops.)
  asm volatile("s_waitcnt lgkmcnt(0)" ::: "memory");

  // ---- phase 2: per-wave MFMA. Wave w: graphs g0 + w*16 .. +15.
  // D[m=feature][n=graph]: A = W2^T[feature][k], B = z[k][graph].
  const int lane = tid & 63;
  const int w    = tid >> 6;
  const int col  = lane & 15;     // A-row m / B-col n / D-col n
  const int quad = lane >> 4;     // k-subblock selector; D-row = quad*4+r

  short8 bfrag[2];
  #pragma unroll
  for (int s = 0; s < 2; ++s)
    bfrag[s] = *(const short8*)&zb[(w * 16 + col) * ZS + s * 32 + quad * 8];

  // C-init = b2 broadcast along the graph (column) dimension: D row is the
  // feature index, so acc[nt][r] needs b2[nt*16 + quad*4 + r].
  float4v acc[8];
  #pragma unroll
  for (int nt = 0; nt < 8; ++nt)
    acc[nt] = *(const float4v*)&sb2[nt * 16 + quad * 4];

  #pragma unroll
  for (int s = 0; s < 2; ++s) {
    #pragma unroll
    for (int nt = 0; nt < 8; ++nt) {
      short8 afrag = *(const short8*)&w2t[(nt * 16 + col) * ZS + s * 32 + quad * 8];
      acc[nt] = __builtin_amdgcn_mfma_f32_16x16x32_bf16(afrag, bfrag[s], acc[nt], 0, 0, 0);
    }
  }

  // ---- epilogue: pure float4 stores (bias already in C). Lane owns 4
  // consecutive features of one graph.
  const int gout = g0 + w * 16 + col;
  if (gout < G) {
    #pragma unroll
    for (int nt = 0; nt < 8; ++nt) {
      float4 v = make_float4(acc[nt][0], acc[nt][1], acc[nt][2], acc[nt][3]);
      *(float4*)&out[gout * 128 + nt * 16 + quad * 4] = v;
    }
  }
}

extern "C" void kernel_launch(void* const* d_in, const int* in_sizes, int n_in,
                              void* d_out, int out_size, void* d_ws, size_t ws_size,
                              hipStream_t stream) {
  const float* x  = (const float*)d_in[0];
  const float* W1 = (const float*)d_in[1];
  const float* b1 = (const float*)d_in[2];
  const float* W2 = (const float*)d_in[3];
  const float* b2 = (const float*)d_in[4];
  float* out = (float*)d_out;

  const int G = in_sizes[0] / 42;
  const int blocks = (G + 63) / 64;
  hipLaunchKernelGGL(gnn_mfma, dim3(blocks), dim3(256), 0, stream,
                     x, W1, b1, W2, b2, out, G);
}